// Round 18
// baseline (199.588 us; speedup 1.0000x reference)
//
#include <hip/hip_runtime.h>
#include <hip/hip_bf16.h>

typedef __attribute__((ext_vector_type(8))) short short8;     // 8 bf16 (MFMA A/B frag, K=32)
typedef __attribute__((ext_vector_type(4))) float float4v;    // MFMA C/D frag

// ---------------------------------------------------------------------------
// prep_all: all input prep in ONE launch (r16).
//   blocks [0,4096):     x fp32 -> xb bf16 (float4 vectorized)
//   blocks [4096,4352):  RoPE table tab[s][p] = (cos,sin), 512 KB, L2-resident
//   blocks [4352,7424):  Wqkv (1024x3072) -> WqkvT (3072x1024) bf16 transpose
//   blocks [7424,8448):  Wout (1024x1024) -> WoutT transpose
// ---------------------------------------------------------------------------
__global__ __launch_bounds__(256) void prep_all(
    const float* __restrict__ x, __hip_bfloat16* __restrict__ xb,
    float2* __restrict__ tab,
    const float* __restrict__ Wqkv, const float* __restrict__ Wout,
    __hip_bfloat16* __restrict__ WqkvT, __hip_bfloat16* __restrict__ WoutT) {
  __shared__ __hip_bfloat16 tile[32][33];
  const int id = blockIdx.x;
  if (id < 4096) {
    const int i = id * 256 + threadIdx.x;
    const float4 v = *(const float4*)(x + (size_t)i * 4);
    __hip_bfloat16 o[4];
    o[0] = __float2bfloat16(v.x); o[1] = __float2bfloat16(v.y);
    o[2] = __float2bfloat16(v.z); o[3] = __float2bfloat16(v.w);
    *(uint2*)(xb + (size_t)i * 4) = *(const uint2*)o;
    return;
  }
  if (id < 4352) {
    const int i = (id - 4096) * 256 + threadIdx.x;   // 65536
    const int s = i >> 5, p = i & 31;
    const float freq = powf(10000.f, -(float)(p * 2) / 64.f);
    float sn, cs;
    sincosf((float)s * freq, &sn, &cs);
    tab[i] = make_float2(cs, sn);
    return;
  }
  const float* in;
  __hip_bfloat16* out;
  int C, bx, by;
  if (id < 7424) {
    const int lid = id - 4352;
    in = Wqkv; out = WqkvT; C = 3072; bx = lid % 96; by = lid / 96;
  } else {
    const int lid = id - 7424;
    in = Wout; out = WoutT; C = 1024; bx = lid & 31; by = lid >> 5;
  }
  const int R = 1024;
  const int c0 = bx * 32, r0 = by * 32;
  const int tx = threadIdx.x & 31, ty = threadIdx.x >> 5;  // ty 0..7
  #pragma unroll
  for (int i = ty; i < 32; i += 8)
    tile[i][tx] = __float2bfloat16(in[(size_t)(r0 + i) * C + (c0 + tx)]);
  __syncthreads();
  #pragma unroll
  for (int i = ty; i < 32; i += 8)
    out[(size_t)(c0 + i) * R + (r0 + tx)] = tile[tx][i];
}

// ---------------------------------------------------------------------------
// gemm_bt: C (MxN, OutT) = A (MxK, row-major bf16) @ Bt^T  (Bt is NxK bf16)
// BMxBN tile, BK=64, 256 threads = 4 waves. Single-buffer r6/r12 K-loop —
// the measured optimum (dbuf r13 and BM=64 r15 both regressed).
// global_load_lds width=16 staging, stride-64 LDS + XOR chunk swizzle.
// gemm1: <bf16,128,128> (768 blocks); gemm2: <float,128,64> (512 blocks).
// ---------------------------------------------------------------------------
template <typename OutT, int BM, int BN>
__global__ __launch_bounds__(256) void gemm_bt(
    const __hip_bfloat16* __restrict__ A,
    const __hip_bfloat16* __restrict__ Bt,
    OutT* __restrict__ C,
    int M, int N, int K) {
  __shared__ __hip_bfloat16 lA[BM][64];
  __shared__ __hip_bfloat16 lB[BN][64];
  constexpr int NI = BM / 32, NJ = BN / 32;      // 16-row/col tiles per wave
  const int t = threadIdx.x;
  const int lane = t & 63, wave = t >> 6;
  const int quad = lane >> 4, ln = lane & 15;
  const int m0 = blockIdx.y * BM, n0 = blockIdx.x * BN;
  const int wm = (wave >> 1) * (BM / 2), wn = (wave & 1) * (BN / 2);
  const int srow = lane >> 3;                    // 0..7
  const int schunk = ((lane & 7) ^ srow) * 8;    // swizzled elem offset

  float4v acc[NI][NJ];
  #pragma unroll
  for (int i = 0; i < NI; ++i)
    #pragma unroll
    for (int j = 0; j < NJ; ++j)
      acc[i][j] = (float4v){0.f, 0.f, 0.f, 0.f};

  for (int kt = 0; kt < K; kt += 64) {
    __syncthreads();   // previous iter's frag reads done before DMA overwrite
    #pragma unroll
    for (int g = 0; g < BM / 32; ++g) {
      const int rbase = wave * (BM / 4) + g * 8;
      __builtin_amdgcn_global_load_lds(
          (const __attribute__((address_space(1))) void*)
              (A + (size_t)(m0 + rbase + srow) * K + kt + schunk),
          (__attribute__((address_space(3))) void*)&lA[rbase][0], 16, 0, 0);
    }
    #pragma unroll
    for (int g = 0; g < BN / 32; ++g) {
      const int rbase = wave * (BN / 4) + g * 8;
      __builtin_amdgcn_global_load_lds(
          (const __attribute__((address_space(1))) void*)
              (Bt + (size_t)(n0 + rbase + srow) * K + kt + schunk),
          (__attribute__((address_space(3))) void*)&lB[rbase][0], 16, 0, 0);
    }
    __syncthreads();   // vmcnt(0) drain: DMA complete, LDS visible
    #pragma unroll
    for (int step = 0; step < 2; ++step) {
      short8 af[NI], bf[NJ];
      #pragma unroll
      for (int i = 0; i < NI; ++i)
        af[i] = *(const short8*)&lA[wm + i * 16 + ln][((step * 4 + quad) ^ (ln & 7)) * 8];
      #pragma unroll
      for (int j = 0; j < NJ; ++j)
        bf[j] = *(const short8*)&lB[wn + j * 16 + ln][((step * 4 + quad) ^ (ln & 7)) * 8];
      #pragma unroll
      for (int i = 0; i < NI; ++i)
        #pragma unroll
        for (int j = 0; j < NJ; ++j)
          acc[i][j] = __builtin_amdgcn_mfma_f32_16x16x32_bf16(af[i], bf[j], acc[i][j], 0, 0, 0);
    }
  }
  // Epilogue. C/D layout: row = quad*4 + reg, col = lane&15 (m89/m91-verified).
  #pragma unroll
  for (int i = 0; i < NI; ++i)
    #pragma unroll
    for (int j = 0; j < NJ; ++j)
      #pragma unroll
      for (int r = 0; r < 4; ++r) {
        const int row = m0 + wm + i * 16 + quad * 4 + r;
        const int col = n0 + wn + j * 16 + ln;
        if constexpr (__is_same(OutT, float))
          C[(size_t)row * N + col] = acc[i][j][r];
        else
          C[(size_t)row * N + col] = __float2bfloat16(acc[i][j][r]);
      }
}

// ---------------------------------------------------------------------------
// Fused QKV prep (table-driven, r12 form): rope(Q,K) reshape + V transpose,
// one qkv pass, zero transcendentals. Q scaled by (1/8)*log2(e).
// ---------------------------------------------------------------------------
__global__ __launch_bounds__(256) void qkv_prep(
    const __hip_bfloat16* __restrict__ qkv,
    const float2* __restrict__ tab,
    __hip_bfloat16* __restrict__ Q,
    __hip_bfloat16* __restrict__ K,
    __hip_bfloat16* __restrict__ Vt) {
  __shared__ __hip_bfloat16 tile[64][65];
  const int s0 = blockIdx.x * 64;
  const int bh = blockIdx.y;
  const int h = bh & 15, b = bh >> 4;
  const int t = threadIdx.x;

  const int pr = t & 31, sl = t >> 5;
  const int d0 = pr * 2;
  const float qs = 0.125f * 1.44269504088896340736f;  // (1/8)*log2(e)
  #pragma unroll
  for (int ss = sl; ss < 64; ss += 8) {
    const int s = s0 + ss;
    const float2 cssn = tab[(size_t)s * 32 + pr];
    const float cs = cssn.x, sn = cssn.y;
    const size_t in_base = (size_t)(b * 2048 + s) * 3072;
    const size_t o = ((size_t)bh * 2048 + s) * 64 + d0;

    __hip_bfloat162 q2 = *(const __hip_bfloat162*)&qkv[in_base + h * 64 + d0];
    float x1 = __bfloat162float(q2.x), x2 = __bfloat162float(q2.y);
    __hip_bfloat162 qo;
    qo.x = __float2bfloat16((x1 * cs - x2 * sn) * qs);
    qo.y = __float2bfloat16((x1 * sn + x2 * cs) * qs);
    *(__hip_bfloat162*)&Q[o] = qo;

    __hip_bfloat162 k2 = *(const __hip_bfloat162*)&qkv[in_base + 1024 + h * 64 + d0];
    x1 = __bfloat162float(k2.x); x2 = __bfloat162float(k2.y);
    __hip_bfloat162 ko;
    ko.x = __float2bfloat16(x1 * cs - x2 * sn);
    ko.y = __float2bfloat16(x1 * sn + x2 * cs);
    *(__hip_bfloat162*)&K[o] = ko;
  }

  const int tx = t & 63, ty = t >> 6;  // ty 0..3
  #pragma unroll
  for (int i = ty; i < 64; i += 4)
    tile[i][tx] = qkv[(size_t)(b * 2048 + s0 + i) * 3072 + 2048 + h * 64 + tx];
  __syncthreads();
  #pragma unroll
  for (int i = ty; i < 64; i += 4)
    Vt[((size_t)bh * 64 + i) * 2048 + s0 + tx] = tile[tx][i];
}

// ---------------------------------------------------------------------------
// Flash-style causal attention — dbuf DMA (r7/r16) with a 128-ROW Q-TILE.
// Total exp/MFMA work is invariant across decompositions (r9/r10/r11/r17
// falsified everything else); what is NOT invariant is staging+barrier
// count. 128-q-tile: each staged K/V tile feeds 2x the MFMA+exp work ->
// block-iterations 16,896 -> ~8,700 (m93's amortization mechanism).
// Wave owns two 16-q groups (g=0: q0+w*16, g=1: q0+64+w*16), processed
// sequentially through the SAME wave-private lP (in-order per wave, no
// barrier) -> LDS stays 41,984 B. Group 0 skips its fully-masked last
// k-tile. Grid 512 (bh fast for XCD spread, longest-first Qt).
// ---------------------------------------------------------------------------
__global__ __launch_bounds__(256) void attention(
    const __hip_bfloat16* __restrict__ Q,
    const __hip_bfloat16* __restrict__ K,
    const __hip_bfloat16* __restrict__ Vt,
    __hip_bfloat16* __restrict__ attn) {
  __shared__ __hip_bfloat16 lK[2][64][64];    // [buf][sk][d]   XOR-swizzled
  __shared__ __hip_bfloat16 lV[2][64][64];    // [buf][d][sk]   XOR-swizzled
  __shared__ __hip_bfloat16 lP[4][16][72];    // per-wave [q][sk], reused per group
  const int t = threadIdx.x;
  const int lane = t & 63, w = t >> 6;
  const int quad = lane >> 4, ln = lane & 15;
  const int id = blockIdx.x;
  const int bh = id & 31;                     // fast index -> XCD spread
  const int Qt = 15 - (id >> 5);              // longest q-tiles first
  const int q0 = Qt * 128;
  const size_t base = (size_t)bh * 2048 * 64;
  const __hip_bfloat16* Qb = Q + base;
  const __hip_bfloat16* Kb = K + base;
  const __hip_bfloat16* Vb = Vt + base;
  const int b = bh >> 4, h = bh & 15;

  short8 ones;
  #pragma unroll
  for (int i = 0; i < 8; ++i) ones[i] = (short)0x3F80;   // bf16 1.0

  const int srow = lane >> 3;
  const int schunk = ((lane & 7) ^ srow) * 8;
  const int rb0 = w * 16;

  // stage kt=0 into buf 0
  #pragma unroll
  for (int g = 0; g < 2; ++g) {
    const int rbase = rb0 + g * 8;
    __builtin_amdgcn_global_load_lds(
        (const __attribute__((address_space(1))) void*)
            (Kb + (size_t)(rbase + srow) * 64 + schunk),
        (__attribute__((address_space(3))) void*)&lK[0][rbase][0], 16, 0, 0);
    __builtin_amdgcn_global_load_lds(
        (const __attribute__((address_space(1))) void*)
            (Vb + (size_t)(rbase + srow) * 2048 + schunk),
        (__attribute__((address_space(3))) void*)&lV[0][rbase][0], 16, 0, 0);
  }

  // Q fragments for both 16-q groups (A-operand: m = ln, k = step*32+quad*8+j)
  short8 qf[2][2];
  #pragma unroll
  for (int g = 0; g < 2; ++g) {
    const size_t qrow = (size_t)(q0 + g * 64 + w * 16 + ln) * 64;
    qf[g][0] = *(const short8*)(Qb + qrow + quad * 8);
    qf[g][1] = *(const short8*)(Qb + qrow + 32 + quad * 8);
  }

  float4v acc_o[2][4];
  #pragma unroll
  for (int g = 0; g < 2; ++g)
    #pragma unroll
    for (int dt = 0; dt < 4; ++dt) acc_o[g][dt] = (float4v){0.f, 0.f, 0.f, 0.f};
  float4v acc_l[2];
  acc_l[0] = (float4v){0.f, 0.f, 0.f, 0.f};
  acc_l[1] = (float4v){0.f, 0.f, 0.f, 0.f};

  const int nk = 2 * (Qt + 1);               // k-tiles of 64 covering q0+128 rows
  for (int kt = 0; kt < nk; ++kt) {
    const int buf = kt & 1;
    __syncthreads();   // drains DMA(kt); frees buf^1

    if (kt + 1 < nk) { // prefetch kt+1 into the other buffer — after barrier
      #pragma unroll
      for (int g = 0; g < 2; ++g) {
        const int rbase = rb0 + g * 8;
        __builtin_amdgcn_global_load_lds(
            (const __attribute__((address_space(1))) void*)
                (Kb + (size_t)((kt + 1) * 64 + rbase + srow) * 64 + schunk),
            (__attribute__((address_space(3))) void*)&lK[buf ^ 1][rbase][0], 16, 0, 0);
        __builtin_amdgcn_global_load_lds(
            (const __attribute__((address_space(1))) void*)
                (Vb + (size_t)(rbase + srow) * 2048 + (kt + 1) * 64 + schunk),
            (__attribute__((address_space(3))) void*)&lV[buf ^ 1][rbase][0], 16, 0, 0);
      }
    }

    #pragma unroll
    for (int g = 0; g < 2; ++g) {
      const int qlimit = 2 * Qt + g;          // last k-tile with live scores
      if (kt > qlimit) continue;              // fully masked (g=0, kt=nk-1)

      float4v s4[4];
      #pragma unroll
      for (int nt = 0; nt < 4; ++nt) {
        float4v a = (float4v){0.f, 0.f, 0.f, 0.f};
        #pragma unroll
        for (int step = 0; step < 2; ++step) {
          short8 kf = *(const short8*)&lK[buf][nt * 16 + ln][((step * 4 + quad) ^ (ln & 7)) * 8];
          a = __builtin_amdgcn_mfma_f32_16x16x32_bf16(qf[g][step], kf, a, 0, 0, 0);
        }
        s4[nt] = a;
      }
      if (kt == qlimit) {  // diagonal tile for this group
        #pragma unroll
        for (int nt = 0; nt < 4; ++nt)
          #pragma unroll
          for (int r = 0; r < 4; ++r) {
            const int sk = kt * 64 + nt * 16 + ln;
            const int qr = q0 + g * 64 + w * 16 + quad * 4 + r;
            if (sk > qr) s4[nt][r] = -64.f;
          }
      }
      // P = exp2(S) -> wave-private lP (in-order per wave, no barrier)
      #pragma unroll
      for (int nt = 0; nt < 4; ++nt)
        #pragma unroll
        for (int r = 0; r < 4; ++r)
          lP[w][quad * 4 + r][nt * 16 + ln] = __float2bfloat16(exp2f(s4[nt][r]));
      // O_g += P V ; l_g += P 1
      #pragma unroll
      for (int step = 0; step < 2; ++step) {
        short8 pf = *(const short8*)&lP[w][ln][step * 32 + quad * 8];
        acc_l[g] = __builtin_amdgcn_mfma_f32_16x16x32_bf16(pf, ones, acc_l[g], 0, 0, 0);
        #pragma unroll
        for (int dt = 0; dt < 4; ++dt) {
          short8 vf = *(const short8*)&lV[buf][dt * 16 + ln][((step * 4 + quad) ^ (ln & 7)) * 8];
          acc_o[g][dt] = __builtin_amdgcn_mfma_f32_16x16x32_bf16(pf, vf, acc_o[g][dt], 0, 0, 0);
        }
      }
    }
  }

  // write O / l  to attn in (b, s, h*64+d) layout
  #pragma unroll
  for (int g = 0; g < 2; ++g) {
    float inv_l[4];
    #pragma unroll
    for (int r = 0; r < 4; ++r) inv_l[r] = 1.0f / acc_l[g][r];
    #pragma unroll
    for (int dt = 0; dt < 4; ++dt)
      #pragma unroll
      for (int r = 0; r < 4; ++r) {
        const int qr = q0 + g * 64 + w * 16 + quad * 4 + r;
        const size_t rg = (size_t)(b * 2048 + qr);
        const int col = h * 64 + dt * 16 + ln;
        attn[rg * 1024 + col] = __float2bfloat16(acc_o[g][dt][r] * inv_l[r]);
      }
  }
}

// ---------------------------------------------------------------------------
extern "C" void kernel_launch(void* const* d_in, const int* in_sizes, int n_in,
                              void* d_out, int out_size, void* d_ws, size_t ws_size,
                              hipStream_t stream) {
  const float* x    = (const float*)d_in[0];  // (2,2048,1024) fp32
  const float* Wqkv = (const float*)d_in[1];  // (1024,3072)   fp32
  const float* Wout = (const float*)d_in[2];  // (1024,1024)   fp32
  float* out = (float*)d_out;                 // (2,2048,1024) fp32

  __hip_bfloat16* ws = (__hip_bfloat16*)d_ws;
  __hip_bfloat16* xb    = ws;                          // 4096*1024
  __hip_bfloat16* WqkvT = xb    + (size_t)4096 * 1024; // 3072*1024
  __hip_bfloat16* WoutT = WqkvT + (size_t)3072 * 1024; // 1024*1024
  __hip_bfloat16* qkv   = WoutT + (size_t)1024 * 1024; // 4096*3072
  __hip_bfloat16* Q     = qkv   + (size_t)4096 * 3072; // 32*2048*64
  __hip_bfloat16* K     = Q     + (size_t)32 * 2048 * 64;
  __hip_bfloat16* Vt    = K     + (size_t)32 * 2048 * 64;
  __hip_bfloat16* attn  = Vt    + (size_t)32 * 2048 * 64;  // dedicated
  float2*         tab   = (float2*)(attn + (size_t)4096 * 1024);  // 2048x32

  prep_all<<<8448, 256, 0, stream>>>(x, xb, tab, Wqkv, Wout, WqkvT, WoutT);
  gemm_bt<__hip_bfloat16, 128, 128><<<dim3(3072 / 128, 4096 / 128), 256, 0, stream>>>(xb, WqkvT, qkv, 4096, 3072, 1024);
  qkv_prep<<<dim3(32, 32), 256, 0, stream>>>(qkv, tab, Q, K, Vt);
  attention<<<512, 256, 0, stream>>>(Q, K, Vt, attn);
  gemm_bt<float, 128, 64><<<dim3(1024 / 64, 4096 / 128), 256, 0, stream>>>(attn, WoutT, out, 4096, 1024, 1024);
}

// Round 19
// 183.779 us; speedup vs baseline: 1.0860x; 1.0860x over previous
//
#include <hip/hip_runtime.h>
#include <hip/hip_bf16.h>

typedef __attribute__((ext_vector_type(8))) short short8;     // 8 bf16 (MFMA A/B frag, K=32)
typedef __attribute__((ext_vector_type(4))) float float4v;    // MFMA C/D frag

// ---------------------------------------------------------------------------
// prep_all: all input prep in ONE launch (r16).
//   blocks [0,4096):     x fp32 -> xb bf16 (float4 vectorized)
//   blocks [4096,4352):  RoPE table tab[s][p] = (cos,sin), 512 KB, L2-resident
//   blocks [4352,7424):  Wqkv (1024x3072) -> WqkvT (3072x1024) bf16 transpose
//   blocks [7424,8448):  Wout (1024x1024) -> WoutT transpose
// ---------------------------------------------------------------------------
__global__ __launch_bounds__(256) void prep_all(
    const float* __restrict__ x, __hip_bfloat16* __restrict__ xb,
    float2* __restrict__ tab,
    const float* __restrict__ Wqkv, const float* __restrict__ Wout,
    __hip_bfloat16* __restrict__ WqkvT, __hip_bfloat16* __restrict__ WoutT) {
  __shared__ __hip_bfloat16 tile[32][33];
  const int id = blockIdx.x;
  if (id < 4096) {
    const int i = id * 256 + threadIdx.x;
    const float4 v = *(const float4*)(x + (size_t)i * 4);
    __hip_bfloat16 o[4];
    o[0] = __float2bfloat16(v.x); o[1] = __float2bfloat16(v.y);
    o[2] = __float2bfloat16(v.z); o[3] = __float2bfloat16(v.w);
    *(uint2*)(xb + (size_t)i * 4) = *(const uint2*)o;
    return;
  }
  if (id < 4352) {
    const int i = (id - 4096) * 256 + threadIdx.x;   // 65536
    const int s = i >> 5, p = i & 31;
    const float freq = powf(10000.f, -(float)(p * 2) / 64.f);
    float sn, cs;
    sincosf((float)s * freq, &sn, &cs);
    tab[i] = make_float2(cs, sn);
    return;
  }
  const float* in;
  __hip_bfloat16* out;
  int C, bx, by;
  if (id < 7424) {
    const int lid = id - 4352;
    in = Wqkv; out = WqkvT; C = 3072; bx = lid % 96; by = lid / 96;
  } else {
    const int lid = id - 7424;
    in = Wout; out = WoutT; C = 1024; bx = lid & 31; by = lid >> 5;
  }
  const int R = 1024;
  const int c0 = bx * 32, r0 = by * 32;
  const int tx = threadIdx.x & 31, ty = threadIdx.x >> 5;  // ty 0..7
  #pragma unroll
  for (int i = ty; i < 32; i += 8)
    tile[i][tx] = __float2bfloat16(in[(size_t)(r0 + i) * C + (c0 + tx)]);
  __syncthreads();
  #pragma unroll
  for (int i = ty; i < 32; i += 8)
    out[(size_t)(c0 + i) * R + (r0 + tx)] = tile[tx][i];
}

// ---------------------------------------------------------------------------
// gemm_bt: C (MxN, OutT) = A (MxK, row-major bf16) @ Bt^T  (Bt is NxK bf16)
// BMxBN tile, BK=64, 256 threads = 4 waves. Single-buffer r6/r12 K-loop —
// the measured optimum (dbuf r13 and BM=64 r15 both regressed).
// global_load_lds width=16 staging, stride-64 LDS + XOR chunk swizzle.
// gemm1: <bf16,128,128> (768 blocks); gemm2: <float,128,64> (512 blocks).
// ---------------------------------------------------------------------------
template <typename OutT, int BM, int BN>
__global__ __launch_bounds__(256) void gemm_bt(
    const __hip_bfloat16* __restrict__ A,
    const __hip_bfloat16* __restrict__ Bt,
    OutT* __restrict__ C,
    int M, int N, int K) {
  __shared__ __hip_bfloat16 lA[BM][64];
  __shared__ __hip_bfloat16 lB[BN][64];
  constexpr int NI = BM / 32, NJ = BN / 32;      // 16-row/col tiles per wave
  const int t = threadIdx.x;
  const int lane = t & 63, wave = t >> 6;
  const int quad = lane >> 4, ln = lane & 15;
  const int m0 = blockIdx.y * BM, n0 = blockIdx.x * BN;
  const int wm = (wave >> 1) * (BM / 2), wn = (wave & 1) * (BN / 2);
  const int srow = lane >> 3;                    // 0..7
  const int schunk = ((lane & 7) ^ srow) * 8;    // swizzled elem offset

  float4v acc[NI][NJ];
  #pragma unroll
  for (int i = 0; i < NI; ++i)
    #pragma unroll
    for (int j = 0; j < NJ; ++j)
      acc[i][j] = (float4v){0.f, 0.f, 0.f, 0.f};

  for (int kt = 0; kt < K; kt += 64) {
    __syncthreads();   // previous iter's frag reads done before DMA overwrite
    #pragma unroll
    for (int g = 0; g < BM / 32; ++g) {
      const int rbase = wave * (BM / 4) + g * 8;
      __builtin_amdgcn_global_load_lds(
          (const __attribute__((address_space(1))) void*)
              (A + (size_t)(m0 + rbase + srow) * K + kt + schunk),
          (__attribute__((address_space(3))) void*)&lA[rbase][0], 16, 0, 0);
    }
    #pragma unroll
    for (int g = 0; g < BN / 32; ++g) {
      const int rbase = wave * (BN / 4) + g * 8;
      __builtin_amdgcn_global_load_lds(
          (const __attribute__((address_space(1))) void*)
              (Bt + (size_t)(n0 + rbase + srow) * K + kt + schunk),
          (__attribute__((address_space(3))) void*)&lB[rbase][0], 16, 0, 0);
    }
    __syncthreads();   // vmcnt(0) drain: DMA complete, LDS visible
    #pragma unroll
    for (int step = 0; step < 2; ++step) {
      short8 af[NI], bf[NJ];
      #pragma unroll
      for (int i = 0; i < NI; ++i)
        af[i] = *(const short8*)&lA[wm + i * 16 + ln][((step * 4 + quad) ^ (ln & 7)) * 8];
      #pragma unroll
      for (int j = 0; j < NJ; ++j)
        bf[j] = *(const short8*)&lB[wn + j * 16 + ln][((step * 4 + quad) ^ (ln & 7)) * 8];
      #pragma unroll
      for (int i = 0; i < NI; ++i)
        #pragma unroll
        for (int j = 0; j < NJ; ++j)
          acc[i][j] = __builtin_amdgcn_mfma_f32_16x16x32_bf16(af[i], bf[j], acc[i][j], 0, 0, 0);
    }
  }
  // Epilogue. C/D layout: row = quad*4 + reg, col = lane&15 (m89/m91-verified).
  #pragma unroll
  for (int i = 0; i < NI; ++i)
    #pragma unroll
    for (int j = 0; j < NJ; ++j)
      #pragma unroll
      for (int r = 0; r < 4; ++r) {
        const int row = m0 + wm + i * 16 + quad * 4 + r;
        const int col = n0 + wn + j * 16 + ln;
        if constexpr (__is_same(OutT, float))
          C[(size_t)row * N + col] = acc[i][j][r];
        else
          C[(size_t)row * N + col] = __float2bfloat16(acc[i][j][r]);
      }
}

// ---------------------------------------------------------------------------
// Fused QKV prep (table-driven, r12 form): rope(Q,K) reshape + V transpose,
// one qkv pass, zero transcendentals. Q scaled by (1/8)*log2(e).
// ---------------------------------------------------------------------------
__global__ __launch_bounds__(256) void qkv_prep(
    const __hip_bfloat16* __restrict__ qkv,
    const float2* __restrict__ tab,
    __hip_bfloat16* __restrict__ Q,
    __hip_bfloat16* __restrict__ K,
    __hip_bfloat16* __restrict__ Vt) {
  __shared__ __hip_bfloat16 tile[64][65];
  const int s0 = blockIdx.x * 64;
  const int bh = blockIdx.y;
  const int h = bh & 15, b = bh >> 4;
  const int t = threadIdx.x;

  const int pr = t & 31, sl = t >> 5;
  const int d0 = pr * 2;
  const float qs = 0.125f * 1.44269504088896340736f;  // (1/8)*log2(e)
  #pragma unroll
  for (int ss = sl; ss < 64; ss += 8) {
    const int s = s0 + ss;
    const float2 cssn = tab[(size_t)s * 32 + pr];
    const float cs = cssn.x, sn = cssn.y;
    const size_t in_base = (size_t)(b * 2048 + s) * 3072;
    const size_t o = ((size_t)bh * 2048 + s) * 64 + d0;

    __hip_bfloat162 q2 = *(const __hip_bfloat162*)&qkv[in_base + h * 64 + d0];
    float x1 = __bfloat162float(q2.x), x2 = __bfloat162float(q2.y);
    __hip_bfloat162 qo;
    qo.x = __float2bfloat16((x1 * cs - x2 * sn) * qs);
    qo.y = __float2bfloat16((x1 * sn + x2 * cs) * qs);
    *(__hip_bfloat162*)&Q[o] = qo;

    __hip_bfloat162 k2 = *(const __hip_bfloat162*)&qkv[in_base + 1024 + h * 64 + d0];
    x1 = __bfloat162float(k2.x); x2 = __bfloat162float(k2.y);
    __hip_bfloat162 ko;
    ko.x = __float2bfloat16(x1 * cs - x2 * sn);
    ko.y = __float2bfloat16(x1 * sn + x2 * cs);
    *(__hip_bfloat162*)&K[o] = ko;
  }

  const int tx = t & 63, ty = t >> 6;  // ty 0..3
  #pragma unroll
  for (int i = ty; i < 64; i += 4)
    tile[i][tx] = qkv[(size_t)(b * 2048 + s0 + i) * 3072 + 2048 + h * 64 + tx];
  __syncthreads();
  #pragma unroll
  for (int i = ty; i < 64; i += 4)
    Vt[((size_t)bh * 64 + i) * 2048 + s0 + tx] = tile[tx][i];
}

// ---------------------------------------------------------------------------
// Flash-style causal attention — r7 PAIRED form, the best measured (45.0 µs
// vs 46.9-47.2 unpaired). grid = (bh=32, pair=16); each block does qt = pair
// then qt = 31-pair: exactly 33 k-iters per block, perfectly uniform, and
// linear id % 8 = bh % 8 keeps head->XCD locality. dbuf global_load_lds,
// one barrier/iter, exp2-domain scores, ones-MFMA row-sum, lP round-trip.
// Hypothesis matrix closed: DS-count (r9), LDS-BW (r10), TLP-up (r11/r17),
// single-buffer (r17), S^T-fusion (r9), amortize (r18) all falsified.
// ---------------------------------------------------------------------------
__global__ __launch_bounds__(256) void attention(
    const __hip_bfloat16* __restrict__ Q,
    const __hip_bfloat16* __restrict__ K,
    const __hip_bfloat16* __restrict__ Vt,
    __hip_bfloat16* __restrict__ attn) {
  __shared__ __hip_bfloat16 lK[2][64][64];    // [buf][sk][d]   XOR-swizzled
  __shared__ __hip_bfloat16 lV[2][64][64];    // [buf][d][sk]   XOR-swizzled
  __shared__ __hip_bfloat16 lP[4][16][72];    // per-wave [q][sk]
  const int t = threadIdx.x;
  const int lane = t & 63, w = t >> 6;
  const int quad = lane >> 4, ln = lane & 15;
  const int bh = blockIdx.x;                  // id%8 = bh%8 -> XCD locality
  const int pair = blockIdx.y;
  const size_t base = (size_t)bh * 2048 * 64;
  const __hip_bfloat16* Qb = Q + base;
  const __hip_bfloat16* Kb = K + base;
  const __hip_bfloat16* Vb = Vt + base;
  const int b = bh >> 4, h = bh & 15;

  short8 ones;
  #pragma unroll
  for (int i = 0; i < 8; ++i) ones[i] = (short)0x3F80;   // bf16 1.0

  const int srow = lane >> 3;
  const int schunk = ((lane & 7) ^ srow) * 8;
  const int rb0 = w * 16;

  #pragma unroll
  for (int ph = 0; ph < 2; ++ph) {
    const int qt = (ph == 0) ? pair : 31 - pair;
    const int q0 = qt * 64;

    __syncthreads();   // protect buf0 from previous phase's last compute

    // stage kt=0 into buf 0
    #pragma unroll
    for (int g = 0; g < 2; ++g) {
      const int rbase = rb0 + g * 8;
      __builtin_amdgcn_global_load_lds(
          (const __attribute__((address_space(1))) void*)
              (Kb + (size_t)(rbase + srow) * 64 + schunk),
          (__attribute__((address_space(3))) void*)&lK[0][rbase][0], 16, 0, 0);
      __builtin_amdgcn_global_load_lds(
          (const __attribute__((address_space(1))) void*)
              (Vb + (size_t)(rbase + srow) * 2048 + schunk),
          (__attribute__((address_space(3))) void*)&lV[0][rbase][0], 16, 0, 0);
    }

    // Q fragment (A-operand): m = ln, k = step*32 + quad*8 + j
    short8 qf[2];
    {
      const size_t qrow = (size_t)(q0 + w * 16 + ln) * 64;
      qf[0] = *(const short8*)(Qb + qrow + quad * 8);
      qf[1] = *(const short8*)(Qb + qrow + 32 + quad * 8);
    }

    float4v acc_o[4];
    #pragma unroll
    for (int dt = 0; dt < 4; ++dt) acc_o[dt] = (float4v){0.f, 0.f, 0.f, 0.f};
    float4v acc_l = (float4v){0.f, 0.f, 0.f, 0.f};

    for (int kt = 0; kt <= qt; ++kt) {
      const int buf = kt & 1;
      __syncthreads();   // drains DMA(kt); frees buf^1

      if (kt < qt) {     // prefetch kt+1 into the other buffer — after barrier
        #pragma unroll
        for (int g = 0; g < 2; ++g) {
          const int rbase = rb0 + g * 8;
          __builtin_amdgcn_global_load_lds(
              (const __attribute__((address_space(1))) void*)
                  (Kb + (size_t)((kt + 1) * 64 + rbase + srow) * 64 + schunk),
              (__attribute__((address_space(3))) void*)&lK[buf ^ 1][rbase][0], 16, 0, 0);
          __builtin_amdgcn_global_load_lds(
              (const __attribute__((address_space(1))) void*)
                  (Vb + (size_t)(rbase + srow) * 2048 + (kt + 1) * 64 + schunk),
              (__attribute__((address_space(3))) void*)&lV[buf ^ 1][rbase][0], 16, 0, 0);
        }
      }

      float4v s4[4];
      #pragma unroll
      for (int nt = 0; nt < 4; ++nt) {
        float4v a = (float4v){0.f, 0.f, 0.f, 0.f};
        #pragma unroll
        for (int step = 0; step < 2; ++step) {
          short8 kf = *(const short8*)&lK[buf][nt * 16 + ln][((step * 4 + quad) ^ (ln & 7)) * 8];
          a = __builtin_amdgcn_mfma_f32_16x16x32_bf16(qf[step], kf, a, 0, 0, 0);
        }
        s4[nt] = a;
      }
      if (kt == qt) {  // diagonal tile: causal mask (exp2(-64) ~ 5e-20 -> 0)
        #pragma unroll
        for (int nt = 0; nt < 4; ++nt)
          #pragma unroll
          for (int r = 0; r < 4; ++r) {
            const int sk = kt * 64 + nt * 16 + ln;
            const int qr = q0 + w * 16 + quad * 4 + r;
            if (sk > qr) s4[nt][r] = -64.f;
          }
      }
      // P = exp2(S), straight to LDS in C-layout (wave-private, no barrier)
      #pragma unroll
      for (int nt = 0; nt < 4; ++nt)
        #pragma unroll
        for (int r = 0; r < 4; ++r)
          lP[w][quad * 4 + r][nt * 16 + ln] = __float2bfloat16(exp2f(s4[nt][r]));
      // O += P V ; l += P 1
      #pragma unroll
      for (int step = 0; step < 2; ++step) {
        short8 pf = *(const short8*)&lP[w][ln][step * 32 + quad * 8];
        acc_l = __builtin_amdgcn_mfma_f32_16x16x32_bf16(pf, ones, acc_l, 0, 0, 0);
        #pragma unroll
        for (int dt = 0; dt < 4; ++dt) {
          short8 vf = *(const short8*)&lV[buf][dt * 16 + ln][((step * 4 + quad) ^ (ln & 7)) * 8];
          acc_o[dt] = __builtin_amdgcn_mfma_f32_16x16x32_bf16(pf, vf, acc_o[dt], 0, 0, 0);
        }
      }
    }

    // write O / l  to attn in (b, s, h*64+d) layout
    float inv_l[4];
    #pragma unroll
    for (int r = 0; r < 4; ++r) inv_l[r] = 1.0f / acc_l[r];
    #pragma unroll
    for (int dt = 0; dt < 4; ++dt)
      #pragma unroll
      for (int r = 0; r < 4; ++r) {
        const int qr = q0 + w * 16 + quad * 4 + r;
        const size_t rg = (size_t)(b * 2048 + qr);
        const int col = h * 64 + dt * 16 + ln;
        attn[rg * 1024 + col] = __float2bfloat16(acc_o[dt][r] * inv_l[r]);
      }
  }
}

// ---------------------------------------------------------------------------
extern "C" void kernel_launch(void* const* d_in, const int* in_sizes, int n_in,
                              void* d_out, int out_size, void* d_ws, size_t ws_size,
                              hipStream_t stream) {
  const float* x    = (const float*)d_in[0];  // (2,2048,1024) fp32
  const float* Wqkv = (const float*)d_in[1];  // (1024,3072)   fp32
  const float* Wout = (const float*)d_in[2];  // (1024,1024)   fp32
  float* out = (float*)d_out;                 // (2,2048,1024) fp32

  __hip_bfloat16* ws = (__hip_bfloat16*)d_ws;
  __hip_bfloat16* xb    = ws;                          // 4096*1024
  __hip_bfloat16* WqkvT = xb    + (size_t)4096 * 1024; // 3072*1024
  __hip_bfloat16* WoutT = WqkvT + (size_t)3072 * 1024; // 1024*1024
  __hip_bfloat16* qkv   = WoutT + (size_t)1024 * 1024; // 4096*3072
  __hip_bfloat16* Q     = qkv   + (size_t)4096 * 3072; // 32*2048*64
  __hip_bfloat16* K     = Q     + (size_t)32 * 2048 * 64;
  __hip_bfloat16* Vt    = K     + (size_t)32 * 2048 * 64;
  __hip_bfloat16* attn  = Vt    + (size_t)32 * 2048 * 64;  // dedicated
  float2*         tab   = (float2*)(attn + (size_t)4096 * 1024);  // 2048x32

  prep_all<<<8448, 256, 0, stream>>>(x, xb, tab, Wqkv, Wout, WqkvT, WoutT);
  gemm_bt<__hip_bfloat16, 128, 128><<<dim3(3072 / 128, 4096 / 128), 256, 0, stream>>>(xb, WqkvT, qkv, 4096, 3072, 1024);
  qkv_prep<<<dim3(32, 32), 256, 0, stream>>>(qkv, tab, Q, K, Vt);
  attention<<<dim3(32, 16), 256, 0, stream>>>(Q, K, Vt, attn);
  gemm_bt<float, 128, 64><<<dim3(1024 / 64, 4096 / 128), 256, 0, stream>>>(attn, WoutT, out, 4096, 1024, 1024);
}

// Round 20
// 183.502 us; speedup vs baseline: 1.0877x; 1.0015x over previous
//
#include <hip/hip_runtime.h>
#include <hip/hip_bf16.h>

typedef __attribute__((ext_vector_type(8))) short short8;     // 8 bf16 (MFMA A/B frag, K=32)
typedef __attribute__((ext_vector_type(4))) float float4v;    // MFMA C/D frag

// ---------------------------------------------------------------------------
// prep_all: all input prep in ONE launch (r16).
//   blocks [0,4096):     x fp32 -> xb bf16 (float4 vectorized)
//   blocks [4096,4352):  RoPE table tab[s][p] = (cos,sin), 512 KB, L2-resident
//   blocks [4352,7424):  Wqkv (1024x3072) -> WqkvT (3072x1024) bf16 transpose
//   blocks [7424,8448):  Wout (1024x1024) -> WoutT transpose
// ---------------------------------------------------------------------------
__global__ __launch_bounds__(256) void prep_all(
    const float* __restrict__ x, __hip_bfloat16* __restrict__ xb,
    float2* __restrict__ tab,
    const float* __restrict__ Wqkv, const float* __restrict__ Wout,
    __hip_bfloat16* __restrict__ WqkvT, __hip_bfloat16* __restrict__ WoutT) {
  __shared__ __hip_bfloat16 tile[32][33];
  const int id = blockIdx.x;
  if (id < 4096) {
    const int i = id * 256 + threadIdx.x;
    const float4 v = *(const float4*)(x + (size_t)i * 4);
    __hip_bfloat16 o[4];
    o[0] = __float2bfloat16(v.x); o[1] = __float2bfloat16(v.y);
    o[2] = __float2bfloat16(v.z); o[3] = __float2bfloat16(v.w);
    *(uint2*)(xb + (size_t)i * 4) = *(const uint2*)o;
    return;
  }
  if (id < 4352) {
    const int i = (id - 4096) * 256 + threadIdx.x;   // 65536
    const int s = i >> 5, p = i & 31;
    const float freq = powf(10000.f, -(float)(p * 2) / 64.f);
    float sn, cs;
    sincosf((float)s * freq, &sn, &cs);
    tab[i] = make_float2(cs, sn);
    return;
  }
  const float* in;
  __hip_bfloat16* out;
  int C, bx, by;
  if (id < 7424) {
    const int lid = id - 4352;
    in = Wqkv; out = WqkvT; C = 3072; bx = lid % 96; by = lid / 96;
  } else {
    const int lid = id - 7424;
    in = Wout; out = WoutT; C = 1024; bx = lid & 31; by = lid >> 5;
  }
  const int R = 1024;
  const int c0 = bx * 32, r0 = by * 32;
  const int tx = threadIdx.x & 31, ty = threadIdx.x >> 5;  // ty 0..7
  #pragma unroll
  for (int i = ty; i < 32; i += 8)
    tile[i][tx] = __float2bfloat16(in[(size_t)(r0 + i) * C + (c0 + tx)]);
  __syncthreads();
  #pragma unroll
  for (int i = ty; i < 32; i += 8)
    out[(size_t)(c0 + i) * R + (r0 + tx)] = tile[tx][i];
}

// ---------------------------------------------------------------------------
// gemm_bt: C (MxN, OutT) = A (MxK, row-major bf16) @ Bt^T  (Bt is NxK bf16)
// BMxBN tile, BK=64, 256 threads = 4 waves. Single-buffer r6/r12 K-loop —
// the measured optimum (dbuf r13 and BM=64 r15 both regressed).
// global_load_lds width=16 staging, stride-64 LDS + XOR chunk swizzle.
// gemm1: <bf16,128,128> (768 blocks); gemm2: <float,128,64> (512 blocks).
// ---------------------------------------------------------------------------
template <typename OutT, int BM, int BN>
__global__ __launch_bounds__(256) void gemm_bt(
    const __hip_bfloat16* __restrict__ A,
    const __hip_bfloat16* __restrict__ Bt,
    OutT* __restrict__ C,
    int M, int N, int K) {
  __shared__ __hip_bfloat16 lA[BM][64];
  __shared__ __hip_bfloat16 lB[BN][64];
  constexpr int NI = BM / 32, NJ = BN / 32;      // 16-row/col tiles per wave
  const int t = threadIdx.x;
  const int lane = t & 63, wave = t >> 6;
  const int quad = lane >> 4, ln = lane & 15;
  const int m0 = blockIdx.y * BM, n0 = blockIdx.x * BN;
  const int wm = (wave >> 1) * (BM / 2), wn = (wave & 1) * (BN / 2);
  const int srow = lane >> 3;                    // 0..7
  const int schunk = ((lane & 7) ^ srow) * 8;    // swizzled elem offset

  float4v acc[NI][NJ];
  #pragma unroll
  for (int i = 0; i < NI; ++i)
    #pragma unroll
    for (int j = 0; j < NJ; ++j)
      acc[i][j] = (float4v){0.f, 0.f, 0.f, 0.f};

  for (int kt = 0; kt < K; kt += 64) {
    __syncthreads();   // previous iter's frag reads done before DMA overwrite
    #pragma unroll
    for (int g = 0; g < BM / 32; ++g) {
      const int rbase = wave * (BM / 4) + g * 8;
      __builtin_amdgcn_global_load_lds(
          (const __attribute__((address_space(1))) void*)
              (A + (size_t)(m0 + rbase + srow) * K + kt + schunk),
          (__attribute__((address_space(3))) void*)&lA[rbase][0], 16, 0, 0);
    }
    #pragma unroll
    for (int g = 0; g < BN / 32; ++g) {
      const int rbase = wave * (BN / 4) + g * 8;
      __builtin_amdgcn_global_load_lds(
          (const __attribute__((address_space(1))) void*)
              (Bt + (size_t)(n0 + rbase + srow) * K + kt + schunk),
          (__attribute__((address_space(3))) void*)&lB[rbase][0], 16, 0, 0);
    }
    __syncthreads();   // vmcnt(0) drain: DMA complete, LDS visible
    #pragma unroll
    for (int step = 0; step < 2; ++step) {
      short8 af[NI], bf[NJ];
      #pragma unroll
      for (int i = 0; i < NI; ++i)
        af[i] = *(const short8*)&lA[wm + i * 16 + ln][((step * 4 + quad) ^ (ln & 7)) * 8];
      #pragma unroll
      for (int j = 0; j < NJ; ++j)
        bf[j] = *(const short8*)&lB[wn + j * 16 + ln][((step * 4 + quad) ^ (ln & 7)) * 8];
      #pragma unroll
      for (int i = 0; i < NI; ++i)
        #pragma unroll
        for (int j = 0; j < NJ; ++j)
          acc[i][j] = __builtin_amdgcn_mfma_f32_16x16x32_bf16(af[i], bf[j], acc[i][j], 0, 0, 0);
    }
  }
  // Epilogue. C/D layout: row = quad*4 + reg, col = lane&15 (m89/m91-verified).
  #pragma unroll
  for (int i = 0; i < NI; ++i)
    #pragma unroll
    for (int j = 0; j < NJ; ++j)
      #pragma unroll
      for (int r = 0; r < 4; ++r) {
        const int row = m0 + wm + i * 16 + quad * 4 + r;
        const int col = n0 + wn + j * 16 + ln;
        if constexpr (__is_same(OutT, float))
          C[(size_t)row * N + col] = acc[i][j][r];
        else
          C[(size_t)row * N + col] = __float2bfloat16(acc[i][j][r]);
      }
}

// ---------------------------------------------------------------------------
// Fused QKV prep (table-driven, r12 form): rope(Q,K) reshape + V transpose,
// one qkv pass, zero transcendentals. Q scaled by (1/8)*log2(e).
// ---------------------------------------------------------------------------
__global__ __launch_bounds__(256) void qkv_prep(
    const __hip_bfloat16* __restrict__ qkv,
    const float2* __restrict__ tab,
    __hip_bfloat16* __restrict__ Q,
    __hip_bfloat16* __restrict__ K,
    __hip_bfloat16* __restrict__ Vt) {
  __shared__ __hip_bfloat16 tile[64][65];
  const int s0 = blockIdx.x * 64;
  const int bh = blockIdx.y;
  const int h = bh & 15, b = bh >> 4;
  const int t = threadIdx.x;

  const int pr = t & 31, sl = t >> 5;
  const int d0 = pr * 2;
  const float qs = 0.125f * 1.44269504088896340736f;  // (1/8)*log2(e)
  #pragma unroll
  for (int ss = sl; ss < 64; ss += 8) {
    const int s = s0 + ss;
    const float2 cssn = tab[(size_t)s * 32 + pr];
    const float cs = cssn.x, sn = cssn.y;
    const size_t in_base = (size_t)(b * 2048 + s) * 3072;
    const size_t o = ((size_t)bh * 2048 + s) * 64 + d0;

    __hip_bfloat162 q2 = *(const __hip_bfloat162*)&qkv[in_base + h * 64 + d0];
    float x1 = __bfloat162float(q2.x), x2 = __bfloat162float(q2.y);
    __hip_bfloat162 qo;
    qo.x = __float2bfloat16((x1 * cs - x2 * sn) * qs);
    qo.y = __float2bfloat16((x1 * sn + x2 * cs) * qs);
    *(__hip_bfloat162*)&Q[o] = qo;

    __hip_bfloat162 k2 = *(const __hip_bfloat162*)&qkv[in_base + 1024 + h * 64 + d0];
    x1 = __bfloat162float(k2.x); x2 = __bfloat162float(k2.y);
    __hip_bfloat162 ko;
    ko.x = __float2bfloat16(x1 * cs - x2 * sn);
    ko.y = __float2bfloat16(x1 * sn + x2 * cs);
    *(__hip_bfloat162*)&K[o] = ko;
  }

  const int tx = t & 63, ty = t >> 6;  // ty 0..3
  #pragma unroll
  for (int i = ty; i < 64; i += 4)
    tile[i][tx] = qkv[(size_t)(b * 2048 + s0 + i) * 3072 + 2048 + h * 64 + tx];
  __syncthreads();
  #pragma unroll
  for (int i = ty; i < 64; i += 4)
    Vt[((size_t)bh * 64 + i) * 2048 + s0 + tx] = tile[tx][i];
}

// ---------------------------------------------------------------------------
// Flash-style causal attention — FROZEN at the r16 form (best measured in
// situ: 47 µs; r19's paired grid regressed to ~51, r7's 45.0 not
// reproducible in current pipeline context). 1024 single-qt blocks,
// longest-first (qt = 31 - id/32, bh = id&31 for XCD spread); dbuf
// global_load_lds; one barrier/iter; exp2-domain scores; ones-MFMA row-sum;
// wave-private lP round-trip. Hypothesis matrix closed: DS-count (r9),
// LDS-BW (r10), TLP (r11/r17), S^T-fusion (r9), single-buffer (r17),
// amortize (r18), pairing (r19) all falsified.
// ---------------------------------------------------------------------------
__global__ __launch_bounds__(256) void attention(
    const __hip_bfloat16* __restrict__ Q,
    const __hip_bfloat16* __restrict__ K,
    const __hip_bfloat16* __restrict__ Vt,
    __hip_bfloat16* __restrict__ attn) {
  __shared__ __hip_bfloat16 lK[2][64][64];    // [buf][sk][d]   XOR-swizzled
  __shared__ __hip_bfloat16 lV[2][64][64];    // [buf][d][sk]   XOR-swizzled
  __shared__ __hip_bfloat16 lP[4][16][72];    // per-wave [q][sk]
  const int t = threadIdx.x;
  const int lane = t & 63, w = t >> 6;
  const int quad = lane >> 4, ln = lane & 15;
  const int id = blockIdx.x;
  const int bh = id & 31;                     // fast index -> XCD spread
  const int qt = 31 - (id >> 5);              // longest q-tiles first
  const int q0 = qt * 64;
  const size_t base = (size_t)bh * 2048 * 64;
  const __hip_bfloat16* Qb = Q + base;
  const __hip_bfloat16* Kb = K + base;
  const __hip_bfloat16* Vb = Vt + base;
  const int b = bh >> 4, h = bh & 15;

  short8 ones;
  #pragma unroll
  for (int i = 0; i < 8; ++i) ones[i] = (short)0x3F80;   // bf16 1.0

  const int srow = lane >> 3;
  const int schunk = ((lane & 7) ^ srow) * 8;
  const int rb0 = w * 16;

  #pragma unroll
  for (int g = 0; g < 2; ++g) {
    const int rbase = rb0 + g * 8;
    __builtin_amdgcn_global_load_lds(
        (const __attribute__((address_space(1))) void*)
            (Kb + (size_t)(rbase + srow) * 64 + schunk),
        (__attribute__((address_space(3))) void*)&lK[0][rbase][0], 16, 0, 0);
    __builtin_amdgcn_global_load_lds(
        (const __attribute__((address_space(1))) void*)
            (Vb + (size_t)(rbase + srow) * 2048 + schunk),
        (__attribute__((address_space(3))) void*)&lV[0][rbase][0], 16, 0, 0);
  }

  short8 qf[2];
  {
    const size_t qrow = (size_t)(q0 + w * 16 + ln) * 64;
    qf[0] = *(const short8*)(Qb + qrow + quad * 8);
    qf[1] = *(const short8*)(Qb + qrow + 32 + quad * 8);
  }

  float4v acc_o[4];
  #pragma unroll
  for (int dt = 0; dt < 4; ++dt) acc_o[dt] = (float4v){0.f, 0.f, 0.f, 0.f};
  float4v acc_l = (float4v){0.f, 0.f, 0.f, 0.f};

  for (int kt = 0; kt <= qt; ++kt) {
    const int buf = kt & 1;
    __syncthreads();

    if (kt < qt) {
      #pragma unroll
      for (int g = 0; g < 2; ++g) {
        const int rbase = rb0 + g * 8;
        __builtin_amdgcn_global_load_lds(
            (const __attribute__((address_space(1))) void*)
                (Kb + (size_t)((kt + 1) * 64 + rbase + srow) * 64 + schunk),
            (__attribute__((address_space(3))) void*)&lK[buf ^ 1][rbase][0], 16, 0, 0);
        __builtin_amdgcn_global_load_lds(
            (const __attribute__((address_space(1))) void*)
                (Vb + (size_t)(rbase + srow) * 2048 + (kt + 1) * 64 + schunk),
            (__attribute__((address_space(3))) void*)&lV[buf ^ 1][rbase][0], 16, 0, 0);
      }
    }

    float4v s4[4];
    #pragma unroll
    for (int nt = 0; nt < 4; ++nt) {
      float4v a = (float4v){0.f, 0.f, 0.f, 0.f};
      #pragma unroll
      for (int step = 0; step < 2; ++step) {
        short8 kf = *(const short8*)&lK[buf][nt * 16 + ln][((step * 4 + quad) ^ (ln & 7)) * 8];
        a = __builtin_amdgcn_mfma_f32_16x16x32_bf16(qf[step], kf, a, 0, 0, 0);
      }
      s4[nt] = a;
    }
    if (kt == qt) {
      #pragma unroll
      for (int nt = 0; nt < 4; ++nt)
        #pragma unroll
        for (int r = 0; r < 4; ++r) {
          const int sk = kt * 64 + nt * 16 + ln;
          const int qr = q0 + w * 16 + quad * 4 + r;
          if (sk > qr) s4[nt][r] = -64.f;
        }
    }
    #pragma unroll
    for (int nt = 0; nt < 4; ++nt)
      #pragma unroll
      for (int r = 0; r < 4; ++r)
        lP[w][quad * 4 + r][nt * 16 + ln] = __float2bfloat16(exp2f(s4[nt][r]));
    #pragma unroll
    for (int step = 0; step < 2; ++step) {
      short8 pf = *(const short8*)&lP[w][ln][step * 32 + quad * 8];
      acc_l = __builtin_amdgcn_mfma_f32_16x16x32_bf16(pf, ones, acc_l, 0, 0, 0);
      #pragma unroll
      for (int dt = 0; dt < 4; ++dt) {
        short8 vf = *(const short8*)&lV[buf][dt * 16 + ln][((step * 4 + quad) ^ (ln & 7)) * 8];
        acc_o[dt] = __builtin_amdgcn_mfma_f32_16x16x32_bf16(pf, vf, acc_o[dt], 0, 0, 0);
      }
    }
  }

  float inv_l[4];
  #pragma unroll
  for (int r = 0; r < 4; ++r) inv_l[r] = 1.0f / acc_l[r];
  #pragma unroll
  for (int dt = 0; dt < 4; ++dt)
    #pragma unroll
    for (int r = 0; r < 4; ++r) {
      const int qr = q0 + w * 16 + quad * 4 + r;
      const size_t rg = (size_t)(b * 2048 + qr);
      const int col = h * 64 + dt * 16 + ln;
      attn[rg * 1024 + col] = __float2bfloat16(acc_o[dt][r] * inv_l[r]);
    }
}

// ---------------------------------------------------------------------------
extern "C" void kernel_launch(void* const* d_in, const int* in_sizes, int n_in,
                              void* d_out, int out_size, void* d_ws, size_t ws_size,
                              hipStream_t stream) {
  const float* x    = (const float*)d_in[0];  // (2,2048,1024) fp32
  const float* Wqkv = (const float*)d_in[1];  // (1024,3072)   fp32
  const float* Wout = (const float*)d_in[2];  // (1024,1024)   fp32
  float* out = (float*)d_out;                 // (2,2048,1024) fp32

  __hip_bfloat16* ws = (__hip_bfloat16*)d_ws;
  __hip_bfloat16* xb    = ws;                          // 4096*1024
  __hip_bfloat16* WqkvT = xb    + (size_t)4096 * 1024; // 3072*1024
  __hip_bfloat16* WoutT = WqkvT + (size_t)3072 * 1024; // 1024*1024
  __hip_bfloat16* qkv   = WoutT + (size_t)1024 * 1024; // 4096*3072
  __hip_bfloat16* Q     = qkv   + (size_t)4096 * 3072; // 32*2048*64
  __hip_bfloat16* K     = Q     + (size_t)32 * 2048 * 64;
  __hip_bfloat16* Vt    = K     + (size_t)32 * 2048 * 64;
  __hip_bfloat16* attn  = Vt    + (size_t)32 * 2048 * 64;  // dedicated
  float2*         tab   = (float2*)(attn + (size_t)4096 * 1024);  // 2048x32

  prep_all<<<8448, 256, 0, stream>>>(x, xb, tab, Wqkv, Wout, WqkvT, WoutT);
  gemm_bt<__hip_bfloat16, 128, 128><<<dim3(3072 / 128, 4096 / 128), 256, 0, stream>>>(xb, WqkvT, qkv, 4096, 3072, 1024);
  qkv_prep<<<dim3(32, 32), 256, 0, stream>>>(qkv, tab, Q, K, Vt);
  attention<<<1024, 256, 0, stream>>>(Q, K, Vt, attn);
  gemm_bt<float, 128, 64><<<dim3(1024 / 64, 4096 / 128), 256, 0, stream>>>(attn, WoutT, out, 4096, 1024, 1024);
}